// Round 12
// baseline (1438.209 us; speedup 1.0000x reference)
//
#include <hip/hip_runtime.h>
#include <math.h>
#include <stdint.h>

typedef _Float16 f16;
typedef _Float16 f16x8 __attribute__((ext_vector_type(8)));
typedef float    f32x16 __attribute__((ext_vector_type(16)));

#define NBLK 256
#define NTHR 512
#define MROW 64

// ---- d_ws fragment layout (identical to r6-r11, validated) ----
#define FC1_F 512
#define FC2_F 640
#define ENC_F 656
#define TOT_F 1232
#define TOT_E (TOT_F*512)

#define MFMA32(a,b,c) __builtin_amdgcn_mfma_f32_32x32x16_f16((a),(b),(c),0,0,0)
#define LGKM0() asm volatile("s_waitcnt lgkmcnt(0)" ::: "memory")
#define BARR()  do { __builtin_amdgcn_s_barrier(); asm volatile("" ::: "memory"); } while(0)

__device__ __forceinline__ float sigm(float v){
  return __fdividef(1.0f, 1.0f + __expf(-v));
}
__device__ __forceinline__ float tanh_f(float v){
  float t = fminf(v, 8.0f);
  float e = __expf(2.0f * t);
  return 1.0f - 2.0f * __fdividef(1.0f, e + 1.0f);
}
__device__ __forceinline__ int eX(int row, int k){ return row*128 + (k ^ ((row & 7) << 3)); }

// ---------------- prep: pack weights as fp16 32x32x16 B-fragments (byte-identical r6-r11) ----------------
__global__ void prep_pack(const float* __restrict__ eWih, const float* __restrict__ eWhh,
                          const float* __restrict__ dWih, const float* __restrict__ dWhh,
                          const float* __restrict__ f1W,  const float* __restrict__ f2W,
                          f16* __restrict__ ws16)
{
  int idx = blockIdx.x * 256 + threadIdx.x;
  if (idx >= TOT_E) return;
  int frag = idx >> 9;
  int lo   = idx & 511;
  int l    = lo >> 3;
  int jj   = lo & 7;
  int c32  = l & 31;
  int half = l >> 5;
  int kin  = half*8 + jj;
  float v = 0.0f;
  if (frag < FC1_F){
    int ct = frag >> 6, st = (frag >> 4) & 3, ks = frag & 15;
    int col = ct*32 + c32, k = ks*16 + kin;
    if      (st == 0) v = dWih[col*256 + k]        + dWhh[col*256 + k];
    else if (st == 1) v = dWih[(256+col)*256 + k]  + dWhh[(256+col)*256 + k];
    else if (st == 2) v = dWih[(512+col)*256 + k];
    else              v = dWhh[(512+col)*256 + k];
  } else if (frag < FC2_F){
    int f = frag - FC1_F, ct = f >> 4, ks = f & 15;
    int col = ct*32 + c32, k = ks*16 + kin;
    v = f1W[col*256 + k];
  } else if (frag < ENC_F){
    int ks = frag - FC2_F, k = ks*16 + kin;
    v = (c32 < 2) ? f2W[c32*256 + k] : 0.0f;
  } else {
    int f = frag - ENC_F, ct = f / 72, r = f % 72;
    int col = ct*32 + c32;
    if (r < 24){ int st = r >> 3, ks = r & 7;  v = eWih[(st*256 + col)*128 + ks*16 + kin]; }
    else { r -= 24; int st = r >> 4, ks = r & 15; v = eWhh[(st*256 + col)*256 + ks*16 + kin]; }
  }
  ws16[idx] = (f16)v;
}

// ---------------- fused persistent kernel ----------------
__global__ __launch_bounds__(NTHR, 1)
void fused_net(const float* __restrict__ x,
               const float* __restrict__ emW, const float* __restrict__ emb_,
               const float* __restrict__ evW, const float* __restrict__ evb,
               const float* __restrict__ ebih, const float* __restrict__ ebhh,
               const float* __restrict__ dbih, const float* __restrict__ dbhh,
               const float* __restrict__ f1b, const float* __restrict__ f2b,
               const f16* __restrict__ ws16, float* __restrict__ out)
{
  __shared__ __align__(16) f16 hA[16384];   // [64][256] h ping
  __shared__ __align__(16) f16 hB[16384];   // [64][256] h pong
  __shared__ __align__(16) f16 hC[16384];   // fc1-out (decoder) / xb (encoder)

  const int tid  = threadIdx.x;
  const int r0   = blockIdx.x * MROW;
  const int l    = tid & 63;
  const int wu   = __builtin_amdgcn_readfirstlane(tid >> 6);  // wave-uniform col-tile
  const int c32  = l & 31;
  const int half = l >> 5;
  const int lo8  = l << 3;                   // per-lane element offset into fragments

  f16* hp = hA;
  f16* hq = hB;

  const int abase  = c32*256 + ((half*8) ^ ((l & 7) << 3));
  const int abase2 = abase + 8192;
  const int colm   = wu*32 + c32;

  // wave-uniform (SGPR) weight bases; loads = SGPR base + uniform frag offset + lo8
  const f16* wdec = ws16 + (size_t)(wu*64)*512;
  const f16* wfc1 = ws16 + (size_t)(FC1_F + wu*16)*512;
  const f16* wfc2 = ws16 + (size_t)FC2_F*512;
  const f16* wenc = ws16 + (size_t)(ENC_F + wu*72)*512;

  #define LDW(base, frag) (*(const f16x8*)((base) + (size_t)(frag)*512 + lo8))

  for (int i = tid; i < 16384; i += NTHR) hA[i] = (f16)0.0f;   // h0 = 0

  // =============== ENCODER: 9 GRU steps ===============
  {
    const float ebr = ebih[colm]       + ebhh[colm];
    const float ebz = ebih[256 + colm] + ebhh[256 + colm];
    const float ebn = ebih[512 + colm];
    const float ebh = ebhh[512 + colm];

    f16x8 eb[3][3];
    // preload units 0,1,2 (x-part frag = st*8 + u)
    #pragma unroll
    for (int p = 0; p < 3; ++p)
      #pragma unroll
      for (int st = 0; st < 3; ++st) eb[p][st] = LDW(wenc, st*8 + p);

    #pragma unroll 1
    for (int t = 0; t < 9; ++t){
      f16* xb = hC;
      { // xt = tanh(embedding) -> xb
        int e  = tid & 127;
        int rq = tid >> 7;
        const float* Wp = (t < 8) ? (evW + e*6) : (emW + e*6);
        float bb = (t < 8) ? evb[e] : emb_[e];
        float w0 = Wp[0], w1 = Wp[1], w2 = Wp[2], w3 = Wp[3], w4 = Wp[4], w5 = Wp[5];
        int xo = (t < 8) ? (6 + t*6) : 0;
        #pragma unroll 1
        for (int rr = 0; rr < 16; ++rr){
          int row = rq*16 + rr;
          const float* xs = x + (size_t)(r0 + row)*54 + xo;
          float a = bb + xs[0]*w0 + xs[1]*w1 + xs[2]*w2 + xs[3]*w3 + xs[4]*w4 + xs[5]*w5;
          xb[eX(row, e)] = (f16)tanh_f(a);
        }
      }
      LGKM0(); BARR();

      f32x16 aR[2], aZ[2], aN[2], aH[2];
      #pragma unroll
      for (int rt = 0; rt < 2; ++rt){ aR[rt] = 0.f; aZ[rt] = 0.f; aN[rt] = 0.f; aH[rt] = 0.f; }

      // 24 units: u<8 x-part (A=xb, streams r,z,n), u>=8 h-part (A=hp, streams r,z,h)
      #pragma unroll
      for (int u = 0; u < 24; ++u){
        f16x8 b0 = eb[u % 3][0];
        f16x8 b1 = eb[u % 3][1];
        f16x8 b2 = eb[u % 3][2];
        if (u < 21){                      // refill just-freed slot with unit u+3
          int uu = u + 3;
          #pragma unroll
          for (int st = 0; st < 3; ++st)
            eb[u % 3][st] = LDW(wenc, (uu < 8) ? (st*8 + uu) : (24 + st*16 + (uu - 8)));
        }
        if (u < 8){
          int ao = (c32*128 + ((half*8) ^ ((l & 7) << 3))) ^ (u << 4);
          f16x8 a0 = *(const f16x8*)(xb + ao);
          f16x8 a1 = *(const f16x8*)(xb + ao + 4096);
          aR[0] = MFMA32(a0, b0, aR[0]);  aR[1] = MFMA32(a1, b0, aR[1]);
          aZ[0] = MFMA32(a0, b1, aZ[0]);  aZ[1] = MFMA32(a1, b1, aZ[1]);
          aN[0] = MFMA32(a0, b2, aN[0]);  aN[1] = MFMA32(a1, b2, aN[1]);
        } else {
          int ao = (u - 8) << 4;
          f16x8 a0 = *(const f16x8*)(hp + (abase ^ ao));
          f16x8 a1 = *(const f16x8*)(hp + (abase2 ^ ao));
          aR[0] = MFMA32(a0, b0, aR[0]);  aR[1] = MFMA32(a1, b0, aR[1]);
          aZ[0] = MFMA32(a0, b1, aZ[0]);  aZ[1] = MFMA32(a1, b1, aZ[1]);
          aH[0] = MFMA32(a0, b2, aH[0]);  aH[1] = MFMA32(a1, b2, aH[1]);
        }
      }
      // preload next step's units 0,1,2 (covered by epilogue + barrier + embed)
      if (t < 8){
        #pragma unroll
        for (int p = 0; p < 3; ++p)
          #pragma unroll
          for (int st = 0; st < 3; ++st) eb[p][st] = LDW(wenc, st*8 + p);
      }
      // epilogue -> hq
      #pragma unroll
      for (int rt = 0; rt < 2; ++rt){
        #pragma unroll
        for (int rg = 0; rg < 16; ++rg){
          int rr  = (rg & 3) + 8*(rg >> 2) + 4*half;
          int row = rt*32 + rr;
          int el  = row*256 + (colm ^ ((rr & 7) << 3));
          float rv = sigm(aR[rt][rg] + ebr);
          float zv = sigm(aZ[rt][rg] + ebz);
          float nv = tanh_f(aN[rt][rg] + ebn + rv*(aH[rt][rg] + ebh));
          float ho = (float)hp[el];
          hq[el] = (f16)(nv + zv*(ho - nv));
        }
      }
      LGKM0(); BARR();
      { f16* tmp = hp; hp = hq; hq = tmp; }
    }
  }

  // =============== DECODER: 32 x (GRU + fc1 + fc2) ===============
  const float dbr = dbih[colm]       + dbhh[colm];
  const float dbz = dbih[256 + colm] + dbhh[256 + colm];
  const float dbn = dbih[512 + colm];
  const float dbh = dbhh[512 + colm];
  const float f1bb = f1b[colm];
  const float f2bb = (c32 < 2) ? f2b[c32] : 0.0f;

  // unified depth-3 pipe: slot p holds 4 frags. Prologue: GRU batches 0,1,2.
  f16x8 bp[3][4];
  #pragma unroll
  for (int p = 0; p < 3; ++p)
    #pragma unroll
    for (int st = 0; st < 4; ++st) bp[p][st] = LDW(wdec, st*16 + p);

  #pragma unroll 1
  for (int s = 0; s < 32; ++s){
    // ---- GRU: reads hp, writes h_new -> hq; B from bp[u%3] ----
    // slot schedule: u reads slot u%3 (holds GRU batch u); refill u<13 -> batch u+3,
    // u=13,14,15 -> FC1 groups 0,1,2 land in slots 1,2,0.
    {
      f32x16 aR[2], aZ[2], aN[2], aH[2];
      #pragma unroll
      for (int rt = 0; rt < 2; ++rt){ aR[rt] = 0.f; aZ[rt] = 0.f; aN[rt] = 0.f; aH[rt] = 0.f; }

      #pragma unroll
      for (int u = 0; u < 16; ++u){
        f16x8 b0 = bp[u % 3][0];
        f16x8 b1 = bp[u % 3][1];
        f16x8 b2 = bp[u % 3][2];
        f16x8 b3 = bp[u % 3][3];
        if (u < 13){                       // refill with GRU batch u+3
          #pragma unroll
          for (int st = 0; st < 4; ++st) bp[u % 3][st] = LDW(wdec, st*16 + u + 3);
        } else {                            // u=13,14,15 -> FC1 groups 0,1,2
          int g = u - 13;
          #pragma unroll
          for (int p = 0; p < 4; ++p) bp[u % 3][p] = LDW(wfc1, g*4 + p);
        }
        int ao = u << 4;
        f16x8 a0 = *(const f16x8*)(hp + (abase  ^ ao));
        f16x8 a1 = *(const f16x8*)(hp + (abase2 ^ ao));
        aR[0] = MFMA32(a0, b0, aR[0]);  aR[1] = MFMA32(a1, b0, aR[1]);
        aZ[0] = MFMA32(a0, b1, aZ[0]);  aZ[1] = MFMA32(a1, b1, aZ[1]);
        aN[0] = MFMA32(a0, b2, aN[0]);  aN[1] = MFMA32(a1, b2, aN[1]);
        aH[0] = MFMA32(a0, b3, aH[0]);  aH[1] = MFMA32(a1, b3, aH[1]);
      }
      #pragma unroll
      for (int rt = 0; rt < 2; ++rt){
        #pragma unroll
        for (int rg = 0; rg < 16; ++rg){
          int rr  = (rg & 3) + 8*(rg >> 2) + 4*half;
          int row = rt*32 + rr;
          int el  = row*256 + (colm ^ ((rr & 7) << 3));
          float rv = sigm(aR[rt][rg] + dbr);
          float zv = sigm(aZ[rt][rg] + dbz);
          float nv = tanh_f(aN[rt][rg] + dbn + rv*(aH[rt][rg] + dbh));
          float ho = (float)hp[el];
          hq[el] = (f16)(nv + zv*(ho - nv));
        }
      }
    }
    LGKM0(); BARR();

    // ---- FC1: relu(h_new @ W1.T + b1): reads hq, writes -> hC ----
    // f reads slot (f+1)%3: f=0->slot1(g0), f=1->slot2(g1), f=2->slot0(g2), f=3->slot1(g3);
    // slot1 is refilled with g3 AFTER f=0 captures its values.
    {
      f32x16 aF0 = 0.f, aF1 = 0.f;
      #pragma unroll
      for (int f = 0; f < 4; ++f){
        f16x8 cc0 = bp[(f + 1) % 3][0];
        f16x8 cc1 = bp[(f + 1) % 3][1];
        f16x8 cc2 = bp[(f + 1) % 3][2];
        f16x8 cc3 = bp[(f + 1) % 3][3];
        if (f == 0){                       // refill slot 1 with FC1 group 3 (after capture)
          #pragma unroll
          for (int p = 0; p < 4; ++p) bp[1][p] = LDW(wfc1, 12 + p);
        }
        int kb = f*4;
        f16x8 a0 = *(const f16x8*)(hq + (abase  ^ ((kb + 0) << 4)));
        f16x8 a1 = *(const f16x8*)(hq + (abase2 ^ ((kb + 0) << 4)));
        aF0 = MFMA32(a0, cc0, aF0);  aF1 = MFMA32(a1, cc0, aF1);
        f16x8 a2 = *(const f16x8*)(hq + (abase  ^ ((kb + 1) << 4)));
        f16x8 a3 = *(const f16x8*)(hq + (abase2 ^ ((kb + 1) << 4)));
        aF0 = MFMA32(a2, cc1, aF0);  aF1 = MFMA32(a3, cc1, aF1);
        f16x8 a4 = *(const f16x8*)(hq + (abase  ^ ((kb + 2) << 4)));
        f16x8 a5 = *(const f16x8*)(hq + (abase2 ^ ((kb + 2) << 4)));
        aF0 = MFMA32(a4, cc2, aF0);  aF1 = MFMA32(a5, cc2, aF1);
        f16x8 a6 = *(const f16x8*)(hq + (abase  ^ ((kb + 3) << 4)));
        f16x8 a7 = *(const f16x8*)(hq + (abase2 ^ ((kb + 3) << 4)));
        aF0 = MFMA32(a6, cc3, aF0);  aF1 = MFMA32(a7, cc3, aF1);
      }
      // refill for next step: GRU batches 0,1,2 -> slots 0,1,2 (covered by epilogue+FC2)
      #pragma unroll
      for (int p = 0; p < 3; ++p)
        #pragma unroll
        for (int st = 0; st < 4; ++st) bp[p][st] = LDW(wdec, st*16 + p);

      #pragma unroll
      for (int rg = 0; rg < 16; ++rg){
        int rr  = (rg & 3) + 8*(rg >> 2) + 4*half;
        int cs  = colm ^ ((rr & 7) << 3);
        hC[rr*256 + cs]        = (f16)fmaxf(aF0[rg] + f1bb, 0.0f);
        hC[(32 + rr)*256 + cs] = (f16)fmaxf(aF1[rg] + f1bb, 0.0f);
      }
    }
    LGKM0(); BARR();

    // ---- FC2 (waves 0-1): y = tanh(hC @ W2.T + b2) -> out; overlaps next GRU ----
    if (wu < 2){
      f32x16 a2 = 0.f;
      f16x8 bv[4];
      #pragma unroll
      for (int p = 0; p < 4; ++p) bv[p] = LDW(wfc2, p);
      #pragma unroll
      for (int g = 0; g < 4; ++g){
        f16x8 cur0 = bv[0], cur1 = bv[1], cur2 = bv[2], cur3 = bv[3];
        if (g < 3){
          #pragma unroll
          for (int p = 0; p < 4; ++p) bv[p] = LDW(wfc2, (g + 1)*4 + p);
        }
        int kb = g*4;
        f16x8 a0 = *(const f16x8*)(hC + ((abase + wu*8192) ^ ((kb + 0) << 4)));
        a2 = MFMA32(a0, cur0, a2);
        f16x8 a1 = *(const f16x8*)(hC + ((abase + wu*8192) ^ ((kb + 1) << 4)));
        a2 = MFMA32(a1, cur1, a2);
        f16x8 a2v = *(const f16x8*)(hC + ((abase + wu*8192) ^ ((kb + 2) << 4)));
        a2 = MFMA32(a2v, cur2, a2);
        f16x8 a3 = *(const f16x8*)(hC + ((abase + wu*8192) ^ ((kb + 3) << 4)));
        a2 = MFMA32(a3, cur3, a2);
      }
      if (c32 < 2){
        #pragma unroll
        for (int rg = 0; rg < 16; ++rg){
          int row = wu*32 + (rg & 3) + 8*(rg >> 2) + 4*half;
          out[((size_t)(r0 + row)*32 + s)*2 + c32] = tanh_f(a2[rg] + f2bb);
        }
      }
    }
    // no barrier: next GRU reads hp(stable)/writes hq(dead); FC2 reads hC — disjoint.
    { f16* tmp = hp; hp = hq; hq = tmp; }
  }
  #undef LDW
}

extern "C" void kernel_launch(void* const* d_in, const int* in_sizes, int n_in,
                              void* d_out, int out_size, void* d_ws, size_t ws_size,
                              hipStream_t stream)
{
  (void)in_sizes; (void)n_in; (void)out_size; (void)ws_size;
  const float* x    = (const float*)d_in[0];
  const float* emW  = (const float*)d_in[1];
  const float* emb_ = (const float*)d_in[2];
  const float* evW  = (const float*)d_in[3];
  const float* evb  = (const float*)d_in[4];
  const float* eWih = (const float*)d_in[5];
  const float* eWhh = (const float*)d_in[6];
  const float* ebih = (const float*)d_in[7];
  const float* ebhh = (const float*)d_in[8];
  const float* dWih = (const float*)d_in[9];
  const float* dWhh = (const float*)d_in[10];
  const float* dbih = (const float*)d_in[11];
  const float* dbhh = (const float*)d_in[12];
  const float* f1W  = (const float*)d_in[13];
  const float* f1b  = (const float*)d_in[14];
  const float* f2W  = (const float*)d_in[15];
  const float* f2b  = (const float*)d_in[16];
  float* out = (float*)d_out;
  f16* ws16 = (f16*)d_ws;

  prep_pack<<<(TOT_E + 255)/256, 256, 0, stream>>>(eWih, eWhh, dWih, dWhh, f1W, f2W, ws16);
  fused_net<<<NBLK, NTHR, 0, stream>>>(x, emW, emb_, evW, evb, ebih, ebhh,
                                       dbih, dbhh, f1b, f2b, ws16, out);
}

// Round 13
// 904.138 us; speedup vs baseline: 1.5907x; 1.5907x over previous
//
#include <hip/hip_runtime.h>
#include <math.h>
#include <stdint.h>

typedef _Float16 f16;
typedef _Float16 f16x8 __attribute__((ext_vector_type(8)));
typedef float    f32x16 __attribute__((ext_vector_type(16)));

#define NBLK 256
#define NTHR 512
#define MROW 64

// ---- d_ws fragment layout (identical to r6-r12, validated) ----
#define FC1_F 512
#define FC2_F 640
#define ENC_F 656
#define TOT_F 1232
#define TOT_E (TOT_F*512)

#define MFMA32(a,b,c) __builtin_amdgcn_mfma_f32_32x32x16_f16((a),(b),(c),0,0,0)
#define VMW4()  asm volatile("s_waitcnt vmcnt(4)" ::: "memory")
#define LGKM0() asm volatile("s_waitcnt lgkmcnt(0)" ::: "memory")
#define BARR()  do { __builtin_amdgcn_s_barrier(); asm volatile("" ::: "memory"); } while(0)

__device__ __forceinline__ void gld16(const f16* g, f16* lds){
  __builtin_amdgcn_global_load_lds(
      (const __attribute__((address_space(1))) void*)(uintptr_t)(const void*)g,
      (__attribute__((address_space(3))) void*)(uint32_t)(uintptr_t)(void*)lds,
      16, 0, 0);
}

__device__ __forceinline__ float sigm(float v){
  return __fdividef(1.0f, 1.0f + __expf(-v));
}
__device__ __forceinline__ float tanh_f(float v){
  float t = fminf(v, 8.0f);
  float e = __expf(2.0f * t);
  return 1.0f - 2.0f * __fdividef(1.0f, e + 1.0f);
}
__device__ __forceinline__ int eX(int row, int k){ return row*128 + (k ^ ((row & 7) << 3)); }

// ---------------- prep: pack weights as fp16 32x32x16 B-fragments (byte-identical r6-r12) ----------------
__global__ void prep_pack(const float* __restrict__ eWih, const float* __restrict__ eWhh,
                          const float* __restrict__ dWih, const float* __restrict__ dWhh,
                          const float* __restrict__ f1W,  const float* __restrict__ f2W,
                          f16* __restrict__ ws16)
{
  int idx = blockIdx.x * 256 + threadIdx.x;
  if (idx >= TOT_E) return;
  int frag = idx >> 9;
  int lo   = idx & 511;
  int l    = lo >> 3;
  int jj   = lo & 7;
  int c32  = l & 31;
  int half = l >> 5;
  int kin  = half*8 + jj;
  float v = 0.0f;
  if (frag < FC1_F){
    int ct = frag >> 6, st = (frag >> 4) & 3, ks = frag & 15;
    int col = ct*32 + c32, k = ks*16 + kin;
    if      (st == 0) v = dWih[col*256 + k]        + dWhh[col*256 + k];
    else if (st == 1) v = dWih[(256+col)*256 + k]  + dWhh[(256+col)*256 + k];
    else if (st == 2) v = dWih[(512+col)*256 + k];
    else              v = dWhh[(512+col)*256 + k];
  } else if (frag < FC2_F){
    int f = frag - FC1_F, ct = f >> 4, ks = f & 15;
    int col = ct*32 + c32, k = ks*16 + kin;
    v = f1W[col*256 + k];
  } else if (frag < ENC_F){
    int ks = frag - FC2_F, k = ks*16 + kin;
    v = (c32 < 2) ? f2W[c32*256 + k] : 0.0f;
  } else {
    int f = frag - ENC_F, ct = f / 72, r = f % 72;
    int col = ct*32 + c32;
    if (r < 24){ int st = r >> 3, ks = r & 7;  v = eWih[(st*256 + col)*128 + ks*16 + kin]; }
    else { r -= 24; int st = r >> 4, ks = r & 15; v = eWhh[(st*256 + col)*256 + ks*16 + kin]; }
  }
  ws16[idx] = (f16)v;
}

// ---------------- fused persistent kernel: 2-pass GRU, DMA B, acc<=64 AGPR ----------------
__global__ __launch_bounds__(NTHR, 1)
void fused_net(const float* __restrict__ x,
               const float* __restrict__ emW, const float* __restrict__ emb_,
               const float* __restrict__ evW, const float* __restrict__ evb,
               const float* __restrict__ ebih, const float* __restrict__ ebhh,
               const float* __restrict__ dbih, const float* __restrict__ dbhh,
               const float* __restrict__ f1b, const float* __restrict__ f2b,
               const f16* __restrict__ ws16, float* __restrict__ out)
{
  __shared__ __align__(16) f16 H0[16384];    // [64][256] h ping
  __shared__ __align__(16) f16 H1[16384];    // [64][256] h pong / fc1-out
  __shared__ __align__(16) f16 stg[32768];   // 8 waves x 4 slots x 1024 f16 (2KB slots)
  __shared__ __align__(16) f16 xbuf[8192];   // encoder xt [64][128]

  const int tid  = threadIdx.x;
  const int r0   = blockIdx.x * MROW;
  const int l    = tid & 63;
  const int wu   = __builtin_amdgcn_readfirstlane(tid >> 6);  // wave-uniform col-tile 0..7
  const int c32  = l & 31;
  const int half = l >> 5;

  f16* hp = H0;
  f16* hq = H1;

  const int abase = c32*256 + ((half*8) ^ ((l & 7) << 3));
  const int xabase= c32*128 + ((half*8) ^ ((l & 7) << 3));
  const int colm  = wu*32 + c32;

  f16* slot0 = stg + wu*4096;                // 4 slots x 1024 f16, wave-private

  // per-lane global weight bases (lane l holds 8 f16 at frag*512 + l*8)
  const f16* wdecL = ws16 + (size_t)(wu*64)*512          + (size_t)l*8;
  const f16* wfc1L = ws16 + (size_t)(FC1_F + wu*16)*512  + (size_t)l*8;
  const f16* wfc2L = ws16 + (size_t)FC2_F*512            + (size_t)l*8;
  const f16* wencL = ws16 + (size_t)(ENC_F + wu*72)*512  + (size_t)l*8;

  // ---- uniform 2-frag batch issuers (2KB each = 2 x gld16) ----
  auto enc_issue = [&](int n, int q){     // n in [0,36)
    f16* d = slot0 + q*1024;
    const f16 *g0, *g1;
    if (n < 8)      {                g0 = wencL + (size_t)(     n)*512;  g1 = wencL + (size_t)( 8 + n)*512; } // x: r,z
    else if (n < 24){ int k = n-8;   g0 = wencL + (size_t)(24 + k)*512;  g1 = wencL + (size_t)(40 + k)*512; } // h: r,z
    else if (n < 28){ int j = 2*(n-24); g0 = wencL + (size_t)(16+j)*512; g1 = wencL + (size_t)(17+j)*512; }   // x: n,n
    else            { int k = 2*(n-28); g0 = wencL + (size_t)(56+k)*512; g1 = wencL + (size_t)(57+k)*512; }   // h: hn,hn
    gld16(g0, d); gld16(g1, d + 512);
  };
  auto dec_issue = [&](int n, int q){     // n in [0,40)
    f16* d = slot0 + q*1024;
    const f16 *g0, *g1;
    if (n < 16)      {               g0 = wdecL + (size_t)(     n)*512;  g1 = wdecL + (size_t)(16 + n)*512; } // r,z
    else if (n < 32) { int k = n-16; g0 = wdecL + (size_t)(32 + k)*512;  g1 = wdecL + (size_t)(48 + k)*512; } // in,hn
    else             { int f2 = 2*(n-32); g0 = wfc1L + (size_t)f2*512;   g1 = wfc1L + (size_t)(f2+1)*512; }   // fc1 pair
    gld16(g0, d); gld16(g1, d + 512);
  };

  // prologue: batches 0,1,2 of encoder step 0 in flight ASAP
  enc_issue(0, 0); enc_issue(1, 1); enc_issue(2, 2);

  for (int i = tid; i < 16384; i += NTHR) H0[i] = (f16)0.0f;   // h0 = 0

  // =============== ENCODER: 9 GRU steps, 2-pass ===============
  {
    const float ebr = ebih[colm]       + ebhh[colm];
    const float ebz = ebih[256 + colm] + ebhh[256 + colm];
    const float ebn = ebih[512 + colm];
    const float ebh = ebhh[512 + colm];

    #pragma unroll 1
    for (int t = 0; t < 9; ++t){
      { // xt = tanh(embedding) -> xbuf
        int e  = tid & 127;
        int rq = tid >> 7;
        const float* Wp = (t < 8) ? (evW + e*6) : (emW + e*6);
        float bb = (t < 8) ? evb[e] : emb_[e];
        float w0 = Wp[0], w1 = Wp[1], w2 = Wp[2], w3 = Wp[3], w4 = Wp[4], w5 = Wp[5];
        int xo = (t < 8) ? (6 + t*6) : 0;
        #pragma unroll 1
        for (int rr = 0; rr < 16; ++rr){
          int row = rq*16 + rr;
          const float* xs = x + (size_t)(r0 + row)*54 + xo;
          float a = bb + xs[0]*w0 + xs[1]*w1 + xs[2]*w2 + xs[3]*w3 + xs[4]*w4 + xs[5]*w5;
          xbuf[eX(row, e)] = (f16)tanh_f(a);
        }
      }
      LGKM0(); BARR();   // xbuf (and t=0: H0 init) visible

      f32x16 rvv[2], zvv[2];
      { // ---- pass 1: r,z over x (u 0..7) then h (u 8..23) ----
        f32x16 aR[2], aZ[2];
        aR[0]=0.f; aR[1]=0.f; aZ[0]=0.f; aZ[1]=0.f;
        #pragma unroll 1
        for (int u = 0; u < 24; ++u){
          VMW4();
          int nn = u + 3;
          if (nn < 36) enc_issue(nn, nn & 3);
          else if (t < 8) enc_issue(nn - 36, nn & 3);
          else dec_issue(nn - 36, nn & 3);
          const f16* sp = slot0 + (u & 3)*1024;
          f16x8 b0 = *(const f16x8*)(sp + l*8);
          f16x8 b1 = *(const f16x8*)(sp + 512 + l*8);
          if (u < 8){
            int ao = xabase ^ (u << 4);
            f16x8 a0 = *(const f16x8*)(xbuf + ao);
            f16x8 a1 = *(const f16x8*)(xbuf + ao + 4096);
            aR[0]=MFMA32(a0,b0,aR[0]); aR[1]=MFMA32(a1,b0,aR[1]);
            aZ[0]=MFMA32(a0,b1,aZ[0]); aZ[1]=MFMA32(a1,b1,aZ[1]);
          } else {
            int ao = abase ^ ((u - 8) << 4);
            f16x8 a0 = *(const f16x8*)(hp + ao);
            f16x8 a1 = *(const f16x8*)(hp + ao + 8192);
            aR[0]=MFMA32(a0,b0,aR[0]); aR[1]=MFMA32(a1,b0,aR[1]);
            aZ[0]=MFMA32(a0,b1,aZ[0]); aZ[1]=MFMA32(a1,b1,aZ[1]);
          }
        }
        #pragma unroll
        for (int rt = 0; rt < 2; ++rt)
          #pragma unroll
          for (int rg = 0; rg < 16; ++rg){
            rvv[rt][rg] = sigm(aR[rt][rg] + ebr);
            zvv[rt][rg] = sigm(aZ[rt][rg] + ebz);
          }
      }
      { // ---- pass 2: n (x, m 0..3) and hn (h, m 4..11), units 24..35 ----
        f32x16 aN[2], aH[2];
        aN[0]=0.f; aN[1]=0.f; aH[0]=0.f; aH[1]=0.f;
        #pragma unroll 1
        for (int m = 0; m < 12; ++m){
          int u = 24 + m;
          VMW4();
          int nn = u + 3;
          if (nn < 36) enc_issue(nn, nn & 3);
          else if (t < 8) enc_issue(nn - 36, nn & 3);
          else dec_issue(nn - 36, nn & 3);
          const f16* sp = slot0 + (u & 3)*1024;
          f16x8 b0 = *(const f16x8*)(sp + l*8);
          f16x8 b1 = *(const f16x8*)(sp + 512 + l*8);
          if (m < 4){
            int j = 2*m;
            int ao0 = xabase ^ (j << 4), ao1 = xabase ^ ((j+1) << 4);
            f16x8 a0 = *(const f16x8*)(xbuf + ao0);
            f16x8 a1 = *(const f16x8*)(xbuf + ao0 + 4096);
            aN[0]=MFMA32(a0,b0,aN[0]); aN[1]=MFMA32(a1,b0,aN[1]);
            f16x8 a2 = *(const f16x8*)(xbuf + ao1);
            f16x8 a3 = *(const f16x8*)(xbuf + ao1 + 4096);
            aN[0]=MFMA32(a2,b1,aN[0]); aN[1]=MFMA32(a3,b1,aN[1]);
          } else {
            int k = 2*(m-4);
            int ao0 = abase ^ (k << 4), ao1 = abase ^ ((k+1) << 4);
            f16x8 a0 = *(const f16x8*)(hp + ao0);
            f16x8 a1 = *(const f16x8*)(hp + ao0 + 8192);
            aH[0]=MFMA32(a0,b0,aH[0]); aH[1]=MFMA32(a1,b0,aH[1]);
            f16x8 a2 = *(const f16x8*)(hp + ao1);
            f16x8 a3 = *(const f16x8*)(hp + ao1 + 8192);
            aH[0]=MFMA32(a2,b1,aH[0]); aH[1]=MFMA32(a3,b1,aH[1]);
          }
        }
        // epilogue -> hq
        #pragma unroll
        for (int rt = 0; rt < 2; ++rt){
          #pragma unroll
          for (int rg = 0; rg < 16; ++rg){
            int rr  = (rg & 3) + 8*(rg >> 2) + 4*half;
            int row = rt*32 + rr;
            int el  = row*256 + (colm ^ ((rr & 7) << 3));
            float nv = tanh_f(aN[rt][rg] + ebn + rvv[rt][rg]*(aH[rt][rg] + ebh));
            float ho = (float)hp[el];
            hq[el] = (f16)(nv + zvv[rt][rg]*(ho - nv));
          }
        }
      }
      LGKM0(); BARR();
      { f16* tmp = hp; hp = hq; hq = tmp; }
    }
  }

  // =============== DECODER: 32 x (2-pass GRU + fc1 + fc2) ===============
  const float dbr = dbih[colm]       + dbhh[colm];
  const float dbz = dbih[256 + colm] + dbhh[256 + colm];
  const float dbn = dbih[512 + colm];
  const float dbh = dbhh[512 + colm];
  const float f1bb = f1b[colm];
  const float f2bb = (c32 < 2) ? f2b[c32] : 0.0f;

  #pragma unroll 1
  for (int s = 0; s < 32; ++s){
    f32x16 rvv[2], zvv[2];
    { // ---- GRU pass A: r,z (units 0..15), reads hp ----
      f32x16 aR[2], aZ[2];
      aR[0]=0.f; aR[1]=0.f; aZ[0]=0.f; aZ[1]=0.f;
      #pragma unroll 1
      for (int u = 0; u < 16; ++u){
        VMW4();
        int nn = u + 3;                         // 3..18, all < 40
        dec_issue(nn, nn & 3);
        const f16* sp = slot0 + (u & 3)*1024;
        f16x8 b0 = *(const f16x8*)(sp + l*8);
        f16x8 b1 = *(const f16x8*)(sp + 512 + l*8);
        int ao = abase ^ (u << 4);
        f16x8 a0 = *(const f16x8*)(hp + ao);
        f16x8 a1 = *(const f16x8*)(hp + ao + 8192);
        aR[0]=MFMA32(a0,b0,aR[0]); aR[1]=MFMA32(a1,b0,aR[1]);
        aZ[0]=MFMA32(a0,b1,aZ[0]); aZ[1]=MFMA32(a1,b1,aZ[1]);
      }
      #pragma unroll
      for (int rt = 0; rt < 2; ++rt)
        #pragma unroll
        for (int rg = 0; rg < 16; ++rg){
          rvv[rt][rg] = sigm(aR[rt][rg] + dbr);
          zvv[rt][rg] = sigm(aZ[rt][rg] + dbz);
        }
    }
    { // ---- GRU pass B: n,hn (units 16..31), reads hp, writes h_new -> hq ----
      f32x16 aN[2], aH[2];
      aN[0]=0.f; aN[1]=0.f; aH[0]=0.f; aH[1]=0.f;
      #pragma unroll 1
      for (int u = 16; u < 32; ++u){
        VMW4();
        int nn = u + 3;                         // 19..34, all < 40
        dec_issue(nn, nn & 3);
        const f16* sp = slot0 + (u & 3)*1024;
        f16x8 b0 = *(const f16x8*)(sp + l*8);
        f16x8 b1 = *(const f16x8*)(sp + 512 + l*8);
        int k = u - 16;
        int ao = abase ^ (k << 4);
        f16x8 a0 = *(const f16x8*)(hp + ao);
        f16x8 a1 = *(const f16x8*)(hp + ao + 8192);
        aN[0]=MFMA32(a0,b0,aN[0]); aN[1]=MFMA32(a1,b0,aN[1]);
        aH[0]=MFMA32(a0,b1,aH[0]); aH[1]=MFMA32(a1,b1,aH[1]);
      }
      #pragma unroll
      for (int rt = 0; rt < 2; ++rt){
        #pragma unroll
        for (int rg = 0; rg < 16; ++rg){
          int rr  = (rg & 3) + 8*(rg >> 2) + 4*half;
          int row = rt*32 + rr;
          int el  = row*256 + (colm ^ ((rr & 7) << 3));
          float nv = tanh_f(aN[rt][rg] + dbn + rvv[rt][rg]*(aH[rt][rg] + dbh));
          float ho = (float)hp[el];
          hq[el] = (f16)(nv + zvv[rt][rg]*(ho - nv));
        }
      }
    }
    LGKM0(); BARR();

    { // ---- FC1 (units 32..39, 2 k-steps each): reads hq, writes -> hp ----
      f32x16 aF[2];
      aF[0]=0.f; aF[1]=0.f;
      #pragma unroll 1
      for (int f = 0; f < 8; ++f){
        VMW4();
        int nn = 35 + f;                        // 35..42 -> wrap to next step 0,1,2
        if (nn < 40) dec_issue(nn, nn & 3);
        else         dec_issue(nn - 40, nn & 3);
        const f16* sp = slot0 + (f & 3)*1024;   // (32+f)&3 == f&3
        f16x8 b0 = *(const f16x8*)(sp + l*8);
        f16x8 b1 = *(const f16x8*)(sp + 512 + l*8);
        int k0 = 2*f;
        int ao0 = abase ^ (k0 << 4), ao1 = abase ^ ((k0+1) << 4);
        f16x8 a0 = *(const f16x8*)(hq + ao0);
        f16x8 a1 = *(const f16x8*)(hq + ao0 + 8192);
        aF[0]=MFMA32(a0,b0,aF[0]); aF[1]=MFMA32(a1,b0,aF[1]);
        f16x8 a2 = *(const f16x8*)(hq + ao1);
        f16x8 a3 = *(const f16x8*)(hq + ao1 + 8192);
        aF[0]=MFMA32(a2,b1,aF[0]); aF[1]=MFMA32(a3,b1,aF[1]);
      }
      #pragma unroll
      for (int rt = 0; rt < 2; ++rt){
        #pragma unroll
        for (int rg = 0; rg < 16; ++rg){
          int rr  = (rg & 3) + 8*(rg >> 2) + 4*half;
          int row = rt*32 + rr;
          int el  = row*256 + (colm ^ ((rr & 7) << 3));
          hp[el] = (f16)fmaxf(aF[rt][rg] + f1bb, 0.0f);
        }
      }
    }
    LGKM0(); BARR();

    // ---- FC2 (wave 0 only, all 64 rows): y = tanh(fc1out @ W2.T + b2) -> out ----
    if (wu == 0){
      f32x16 a2r0 = 0.f, a2r1 = 0.f;
      #pragma unroll
      for (int ks = 0; ks < 16; ++ks){
        f16x8 bv = *(const f16x8*)(wfc2L + (size_t)ks*512);
        int ao = abase ^ (ks << 4);
        f16x8 a0 = *(const f16x8*)(hp + ao);
        f16x8 a1 = *(const f16x8*)(hp + ao + 8192);
        a2r0 = MFMA32(a0, bv, a2r0);
        a2r1 = MFMA32(a1, bv, a2r1);
      }
      if (c32 < 2){
        #pragma unroll
        for (int rg = 0; rg < 16; ++rg){
          int rr = (rg & 3) + 8*(rg >> 2) + 4*half;
          out[((size_t)(r0 + rr)*32 + s)*2 + c32]      = tanh_f(a2r0[rg] + f2bb);
          out[((size_t)(r0 + 32 + rr)*32 + s)*2 + c32] = tanh_f(a2r1[rg] + f2bb);
        }
      }
    }
    BARR();   // next pass-B writes the fc1out buffer; FC2 must finish first
    { f16* tmp = hp; hp = hq; hq = tmp; }
  }
}

extern "C" void kernel_launch(void* const* d_in, const int* in_sizes, int n_in,
                              void* d_out, int out_size, void* d_ws, size_t ws_size,
                              hipStream_t stream)
{
  (void)in_sizes; (void)n_in; (void)out_size; (void)ws_size;
  const float* x    = (const float*)d_in[0];
  const float* emW  = (const float*)d_in[1];
  const float* emb_ = (const float*)d_in[2];
  const float* evW  = (const float*)d_in[3];
  const float* evb  = (const float*)d_in[4];
  const float* eWih = (const float*)d_in[5];
  const float* eWhh = (const float*)d_in[6];
  const float* ebih = (const float*)d_in[7];
  const float* ebhh = (const float*)d_in[8];
  const float* dWih = (const float*)d_in[9];
  const float* dWhh = (const float*)d_in[10];
  const float* dbih = (const float*)d_in[11];
  const float* dbhh = (const float*)d_in[12];
  const float* f1W  = (const float*)d_in[13];
  const float* f1b  = (const float*)d_in[14];
  const float* f2W  = (const float*)d_in[15];
  const float* f2b  = (const float*)d_in[16];
  float* out = (float*)d_out;
  f16* ws16 = (f16*)d_ws;

  prep_pack<<<(TOT_E + 255)/256, 256, 0, stream>>>(eWih, eWhh, dWih, dWhh, f1W, f2W, ws16);
  fused_net<<<NBLK, NTHR, 0, stream>>>(x, emW, emb_, evW, evb, ebih, ebhh,
                                       dbih, dbhh, f1b, f2b, ws16, out);
}